// Round 14
// baseline (80.261 us; speedup 1.0000x reference)
//
#include <hip/hip_runtime.h>
#include <math.h>

#define NPATCH 24
#define NB 4
#define MPTS 256
#define MT 4096
#define NPTS (NPATCH*MPTS)   // 6144
#define GRIDPTS 64
#define SIGMA2INV 100.0f
#define PRUNE_MARGIN 0.45f   // exp(-100*0.45^2) ~ 2e-9, negligible vs threshold

// ---------- helpers ----------

__device__ inline unsigned encodeFloat(float f) {
    unsigned u = __float_as_uint(f);
    return (u & 0x80000000u) ? ~u : (u | 0x80000000u);
}
__device__ inline float decodeFloat(unsigned e) {
    return __uint_as_float((e & 0x80000000u) ? (e ^ 0x80000000u) : ~e);
}

__device__ inline unsigned long long waveMinU64(unsigned long long k) {
    for (int o = 32; o > 0; o >>= 1) {
        unsigned long long other = __shfl_xor(k, o);
        k = (other < k) ? other : k;
    }
    return k;
}

template<int NV>
__device__ inline void blockReduceSumN(const float* vals, float* out, float* scratch) {
    int wid = threadIdx.x >> 6, lane = threadIdx.x & 63;
#pragma unroll
    for (int i = 0; i < NV; ++i) {
        float v = vals[i];
        for (int o = 32; o > 0; o >>= 1) v += __shfl_down(v, o);
        if (lane == 0) scratch[wid * NV + i] = v;
    }
    __syncthreads();
    if (threadIdx.x < NV)
        out[threadIdx.x] = scratch[0 * NV + threadIdx.x] + scratch[1 * NV + threadIdx.x] +
                           scratch[2 * NV + threadIdx.x] + scratch[3 * NV + threadIdx.x];
    __syncthreads();
}

__device__ inline float clamp01f(float x) { return fminf(fmaxf(x, 0.0f), 1.0f); }
__device__ inline float safercp(float x) {
    float s = fabsf(x) < 1e-12f ? 1e-12f : x;
    return __builtin_amdgcn_rcpf(s);
}

// point-vs-tri sq distance using precomputed tri data (4 float4 per tri)
__device__ inline float ptTriSqDistP(float px, float py, float pz, const float4* T) {
    float4 f0 = T[0], f1 = T[1], f2 = T[2], f3 = T[3];
    float ax = f0.x, ay = f0.y, az = f0.z;
    float abx = f1.x, aby = f1.y, abz = f1.z;
    float acx = f2.x, acy = f2.y, acz = f2.z;
    float abp = abx * px + aby * py + abz * pz;
    float acp = acx * px + acy * py + acz * pz;
    float d1 = abp - f0.w;
    float d2 = acp - f1.w;
    float d3 = abp - f2.w;
    float d4 = acp - f3.x;
    float d5 = abp - f3.y;
    float d6 = acp - f3.z;
    float vc = d1 * d4 - d3 * d2;
    float vb = d5 * d2 - d1 * d6;
    float va = d3 * d6 - d5 * d4;
    float t_ab = clamp01f(d1 * safercp(d1 - d3));
    float t_ac = clamp01f(d2 * safercp(d2 - d6));
    float t_bc = clamp01f((d4 - d3) * safercp((d4 - d3) + (d5 - d6)));
    float rden = safercp(va + vb + vc);
    float v = vb * rden, w = vc * rden;
    float clx = ax + abx * v + acx * w;
    float cly = ay + aby * v + acy * w;
    float clz = az + abz * v + acz * w;
    if (va <= 0.0f && (d4 - d3) >= 0.0f && (d5 - d6) >= 0.0f) {
        clx = (ax + abx) + (acx - abx) * t_bc;
        cly = (ay + aby) + (acy - aby) * t_bc;
        clz = (az + abz) + (acz - abz) * t_bc;
    }
    if (vb <= 0.0f && d2 >= 0.0f && d6 <= 0.0f) {
        clx = ax + acx * t_ac; cly = ay + acy * t_ac; clz = az + acz * t_ac;
    }
    if (d6 >= 0.0f && d5 <= d6) { clx = ax + acx; cly = ay + acy; clz = az + acz; }
    if (vc <= 0.0f && d1 >= 0.0f && d3 <= 0.0f) {
        clx = ax + abx * t_ab; cly = ay + aby * t_ab; clz = az + abz * t_ab;
    }
    if (d3 >= 0.0f && d4 <= d3) { clx = ax + abx; cly = ay + aby; clz = az + abz; }
    if (d1 <= 0.0f && d2 <= 0.0f) { clx = ax; cly = ay; clz = az; }
    float dx = px - clx, dy = py - cly, dz = pz - clz;
    return dx * dx + dy * dy + dz * dz;
}

// ---------- kernel 1: Coons sampling + bboxes + tri data + ws init (fused) ----------
__global__ __launch_bounds__(128) void k_coons_tri(const float* __restrict__ patches,
                                                   float* __restrict__ grid,
                                                   float* __restrict__ bbF,
                                                   float* __restrict__ bbE,
                                                   float4* __restrict__ TDg,
                                                   float4* __restrict__ TSg,
                                                   unsigned* __restrict__ pairmin,
                                                   float* __restrict__ acc) {
    __shared__ float Pl[192];
    int bp = blockIdx.x;
    int m = threadIdx.x;
    if (bp == 0) {
        for (int i = m; i < 1104; i += 128) pairmin[i] = 0xFFFFFFFFu;
        if (m < 32) acc[m] = 0.0f;
    }
    if (m < 64) {
        int i = m >> 3, j = m & 7;
        float s = (i == 7) ? 1.0f : (float)i * (1.0f / 7.0f);
        float t = (j == 7) ? 1.0f : (float)j * (1.0f / 7.0f);
        const float* cp = patches + bp * 36;
        float bs[4], bt[4], bs1[4], bt1[4];
        {
            float u, vv;
            u = s; vv = 1.0f - u; bs[0] = vv * vv * vv; bs[1] = 3.f * u * vv * vv; bs[2] = 3.f * u * u * vv; bs[3] = u * u * u;
            u = t; vv = 1.0f - u; bt[0] = vv * vv * vv; bt[1] = 3.f * u * vv * vv; bt[2] = 3.f * u * u * vv; bt[3] = u * u * u;
            u = 1.0f - s; vv = 1.0f - u; bs1[0] = vv * vv * vv; bs1[1] = 3.f * u * vv * vv; bs1[2] = 3.f * u * u * vv; bs1[3] = u * u * u;
            u = 1.0f - t; vv = 1.0f - u; bt1[0] = vv * vv * vv; bt1[1] = 3.f * u * vv * vv; bt1[2] = 3.f * u * u * vv; bt1[3] = u * u * u;
        }
        float g[3];
#pragma unroll
        for (int c = 0; c < 3; ++c) {
            float cb = bs[0] * cp[0 * 3 + c] + bs[1] * cp[1 * 3 + c] + bs[2] * cp[2 * 3 + c] + bs[3] * cp[3 * 3 + c];
            float cr = bt[0] * cp[3 * 3 + c] + bt[1] * cp[4 * 3 + c] + bt[2] * cp[5 * 3 + c] + bt[3] * cp[6 * 3 + c];
            float ct = bs1[0] * cp[6 * 3 + c] + bs1[1] * cp[7 * 3 + c] + bs1[2] * cp[8 * 3 + c] + bs1[3] * cp[9 * 3 + c];
            float cl = bt1[0] * cp[9 * 3 + c] + bt1[1] * cp[10 * 3 + c] + bt1[2] * cp[11 * 3 + c] + bt1[3] * cp[0 * 3 + c];
            float P00 = cp[0 * 3 + c], P10 = cp[3 * 3 + c], P11 = cp[6 * 3 + c], P01 = cp[9 * 3 + c];
            float ruled = (1.0f - t) * cb + t * ct + (1.0f - s) * cl + s * cr;
            float bil = (1.0f - s) * (1.0f - t) * P00 + s * (1.0f - t) * P10 + s * t * P11 + (1.0f - s) * t * P01;
            g[c] = ruled - bil;
            grid[(bp * GRIDPTS + m) * 3 + c] = g[c];
            Pl[m * 3 + c] = g[c];
        }
        float mnF[3], mxF[3], mnE[3], mxE[3];
        bool edge = (m >= 56);
#pragma unroll
        for (int c = 0; c < 3; ++c) {
            mnF[c] = g[c]; mxF[c] = g[c];
            mnE[c] = edge ? g[c] : 1e30f;
            mxE[c] = edge ? g[c] : -1e30f;
        }
        for (int o = 32; o > 0; o >>= 1) {
#pragma unroll
            for (int c = 0; c < 3; ++c) {
                mnF[c] = fminf(mnF[c], __shfl_down(mnF[c], o));
                mxF[c] = fmaxf(mxF[c], __shfl_down(mxF[c], o));
                mnE[c] = fminf(mnE[c], __shfl_down(mnE[c], o));
                mxE[c] = fmaxf(mxE[c], __shfl_down(mxE[c], o));
            }
        }
        if (m == 0) {
#pragma unroll
            for (int c = 0; c < 3; ++c) {
                bbF[bp * 6 + c] = mnF[c]; bbF[bp * 6 + 3 + c] = mxF[c];
                bbE[bp * 6 + c] = mnE[c]; bbE[bp * 6 + 3 + c] = mxE[c];
            }
        }
    }
    __syncthreads();
    int t = m;
    if (t < 98) {
        int cell = t >> 1, ii = cell / 7, jj = cell - ii * 7;
        int v00 = ii * 8 + jj;
        int va, vb, vc;
        if (t & 1) { va = v00 + 8; vb = v00 + 9; vc = v00 + 1; }
        else       { va = v00;     vb = v00 + 8; vc = v00 + 1; }
        float ax = Pl[va * 3], ay = Pl[va * 3 + 1], az = Pl[va * 3 + 2];
        float bx = Pl[vb * 3], by = Pl[vb * 3 + 1], bz = Pl[vb * 3 + 2];
        float cx = Pl[vc * 3], cy = Pl[vc * 3 + 1], cz = Pl[vc * 3 + 2];
        float abx = bx - ax, aby = by - ay, abz = bz - az;
        float acx = cx - ax, acy = cy - ay, acz = cz - az;
        float ab_a = abx * ax + aby * ay + abz * az;
        float ac_a = acx * ax + acy * ay + acz * az;
        float ab_b = abx * bx + aby * by + abz * bz;
        float ac_b = acx * bx + acy * by + acz * bz;
        float ab_c = abx * cx + aby * cy + abz * cz;
        float ac_c = acx * cx + acy * cy + acz * cz;
        float4* dst = TDg + ((size_t)bp * 98 + t) * 4;
        dst[0] = make_float4(ax, ay, az, ab_a);
        dst[1] = make_float4(abx, aby, abz, ac_a);
        dst[2] = make_float4(acx, acy, acz, ab_b);
        dst[3] = make_float4(ac_b, ab_c, ac_c, 0.0f);
        float gx = (ax + bx + cx) * (1.0f / 3.0f);
        float gy = (ay + by + cy) * (1.0f / 3.0f);
        float gz = (az + bz + cz) * (1.0f / 3.0f);
        float ra = (ax - gx) * (ax - gx) + (ay - gy) * (ay - gy) + (az - gz) * (az - gz);
        float rb = (bx - gx) * (bx - gx) + (by - gy) * (by - gy) + (bz - gz) * (bz - gz);
        float rc = (cx - gx) * (cx - gx) + (cy - gy) * (cy - gy) + (cz - gz) * (cz - gz);
        float r = sqrtf(fmaxf(ra, fmaxf(rb, rc)));
        TSg[(size_t)bp * 98 + t] = make_float4(gx, gy, gz, r);
    }
}

// ---------- mega kernel (flattened 1-D grid: 2880 blocks; id=idx>>2, b=idx&3) ----------
// ids, LONG chamfer blocks FIRST (LPT packing):
//  [0,96):   chamfer A  qb=id>>5, ch=id&31 (32 target-chunks of 128)
//  [96,192): chamfer B  rel=id-96: qb=rel/48, ch=rel%48 (48 point-chunks of 128)
//  [192,216): collision adjacent
//  [216,720): collision non-adjacent, r=id-216: pair=r>>1, dir=r&1
__global__ __launch_bounds__(256) void k_mega(const float* __restrict__ target,
                                              const float* __restrict__ points,
                                              const float* __restrict__ grid,
                                              const float4* __restrict__ TDg,
                                              const float4* __restrict__ TSg,
                                              const float* __restrict__ bbF,
                                              const float* __restrict__ bbE,
                                              float* __restrict__ pa,
                                              float* __restrict__ pb,
                                              unsigned* __restrict__ pairmin) {
    __shared__ float4 smem[128];
    __shared__ float4 Pts[64];
    __shared__ float4 Sph[98];
    __shared__ unsigned short wl[6272];
    __shared__ int cnt;
    __shared__ float sred[4];
    int idx = blockIdx.x;
    int id = idx >> 2;
    int b = idx & 3;
    int tid = threadIdx.x;

    if (id < 192) {
        bool isA = (id < 96);
        int qbase, ch;
        float qx0, qy0, qz0, qx1, qy1, qz1, qx2, qy2, qz2, qx3, qy3, qz3;
        float qx4, qy4, qz4, qx5, qy5, qz5, qx6, qy6, qz6, qx7, qy7, qz7;
        if (isA) {
            int qb = id >> 5; ch = id & 31;
            qbase = qb * 2048 + tid * 8;
            int chbase = ch * 128;
            if (tid < 128) {
                const float* tp = target + (size_t)(b * MT + chbase + tid) * 6;
                float x = tp[0], y = tp[1], z = tp[2];
                smem[tid] = make_float4(x, y, z, 0.5f * (x * x + y * y + z * z));
            }
            const float4* pf = (const float4*)(points + ((size_t)b * NPTS + qbase) * 3);
            float4 v0 = pf[0], v1 = pf[1], v2 = pf[2], v3 = pf[3], v4 = pf[4], v5 = pf[5];
            qx0 = v0.x; qy0 = v0.y; qz0 = v0.z;
            qx1 = v0.w; qy1 = v1.x; qz1 = v1.y;
            qx2 = v1.z; qy2 = v1.w; qz2 = v2.x;
            qx3 = v2.y; qy3 = v2.z; qz3 = v2.w;
            qx4 = v3.x; qy4 = v3.y; qz4 = v3.z;
            qx5 = v3.w; qy5 = v4.x; qz5 = v4.y;
            qx6 = v4.z; qy6 = v4.w; qz6 = v5.x;
            qx7 = v5.y; qy7 = v5.z; qz7 = v5.w;
        } else {
            int rel = id - 96;
            int qb = rel / 48; ch = rel - qb * 48;
            qbase = qb * 2048 + tid * 8;
            int chbase = ch * 128;
            if (tid < 128) {
                const float* pp = points + (size_t)(b * NPTS + chbase + tid) * 3;
                float x = pp[0], y = pp[1], z = pp[2];
                smem[tid] = make_float4(x, y, z, 0.5f * (x * x + y * y + z * z));
            }
            const float* tf = target + (size_t)(b * MT + qbase) * 6;
            float2 a0 = *(const float2*)(tf + 0);  float z0 = tf[2];
            float2 a1 = *(const float2*)(tf + 6);  float z1 = tf[8];
            float2 a2 = *(const float2*)(tf + 12); float z2 = tf[14];
            float2 a3 = *(const float2*)(tf + 18); float z3 = tf[20];
            float2 a4 = *(const float2*)(tf + 24); float z4 = tf[26];
            float2 a5 = *(const float2*)(tf + 30); float z5 = tf[32];
            float2 a6 = *(const float2*)(tf + 36); float z6 = tf[38];
            float2 a7 = *(const float2*)(tf + 42); float z7 = tf[44];
            qx0 = a0.x; qy0 = a0.y; qz0 = z0;
            qx1 = a1.x; qy1 = a1.y; qz1 = z1;
            qx2 = a2.x; qy2 = a2.y; qz2 = z2;
            qx3 = a3.x; qy3 = a3.y; qz3 = z3;
            qx4 = a4.x; qy4 = a4.y; qz4 = z4;
            qx5 = a5.x; qy5 = a5.y; qz5 = z5;
            qx6 = a6.x; qy6 = a6.y; qz6 = z6;
            qx7 = a7.x; qy7 = a7.y; qz7 = z7;
        }
        __syncthreads();
        float sc0 = 1e30f, sc1 = 1e30f, sc2 = 1e30f, sc3 = 1e30f;
        float sc4 = 1e30f, sc5 = 1e30f, sc6 = 1e30f, sc7 = 1e30f;
#pragma unroll 8
        for (int k = 0; k < 128; ++k) {
            float4 T = smem[k];
            sc0 = fminf(sc0, fmaf(-qx0, T.x, fmaf(-qy0, T.y, fmaf(-qz0, T.z, T.w))));
            sc1 = fminf(sc1, fmaf(-qx1, T.x, fmaf(-qy1, T.y, fmaf(-qz1, T.z, T.w))));
            sc2 = fminf(sc2, fmaf(-qx2, T.x, fmaf(-qy2, T.y, fmaf(-qz2, T.z, T.w))));
            sc3 = fminf(sc3, fmaf(-qx3, T.x, fmaf(-qy3, T.y, fmaf(-qz3, T.z, T.w))));
            sc4 = fminf(sc4, fmaf(-qx4, T.x, fmaf(-qy4, T.y, fmaf(-qz4, T.z, T.w))));
            sc5 = fminf(sc5, fmaf(-qx5, T.x, fmaf(-qy5, T.y, fmaf(-qz5, T.z, T.w))));
            sc6 = fminf(sc6, fmaf(-qx6, T.x, fmaf(-qy6, T.y, fmaf(-qz6, T.z, T.w))));
            sc7 = fminf(sc7, fmaf(-qx7, T.x, fmaf(-qy7, T.y, fmaf(-qz7, T.z, T.w))));
        }
        float* dstp = isA ? (pa + ((size_t)(b * 32 + ch)) * NPTS + qbase)
                          : (pb + ((size_t)(b * 48 + ch)) * MT + qbase);
        *(float4*)(dstp) = make_float4(sc0, sc1, sc2, sc3);
        *(float4*)(dstp + 4) = make_float4(sc4, sc5, sc6, sc7);
        return;
    }

    float best = 1e30f;
    int pairIdx;

    if (id < 216) {
        // ---- collision, adjacent pair ----
        int pair = id - 192;
        pairIdx = pair;
        int i1 = pair, i2 = (pair + 1) % NPATCH;
        bool mask = false;
        for (int bb = 0; bb < NB; ++bb) {
            const float* B1 = bbE + (bb * NPATCH + i1) * 6;
            const float* B2 = bbF + (bb * NPATCH + i2) * 6;
            bool it = (B1[3] >= B2[0]) && (B2[3] >= B1[0]) &&
                      (B1[4] >= B2[1]) && (B2[4] >= B1[1]) &&
                      (B1[5] >= B2[2]) && (B2[5] >= B1[2]);
            mask |= it;
        }
        if (!mask) return;
        const float* P1 = grid + (size_t)(b * NPATCH + i1) * 192;
        const float* P2 = grid + (size_t)(b * NPATCH + i2) * 192;
        const float4* T1 = TDg + (size_t)(b * NPATCH + i1) * 98 * 4;
        const float4* T2 = TDg + (size_t)(b * NPATCH + i2) * 98 * 4;
        for (int tt = tid; tt < 1232; tt += 256) {
            const float4* T;
            float px, py, pz;
            if (tt < 784) {
                int ptI = tt / 98, tri = tt - ptI * 98;
                const float* gp = P1 + (56 + ptI) * 3;
                px = gp[0]; py = gp[1]; pz = gp[2];
                T = T2 + tri * 4;
            } else {
                int rr = tt - 784;
                int ptI = rr / 7, e = rr - ptI * 7;
                const float* gp = P2 + ptI * 3;
                px = gp[0]; py = gp[1]; pz = gp[2];
                T = T1 + (85 + 2 * e) * 4;
            }
            best = fminf(best, ptTriSqDistP(px, py, pz, T));
        }
    } else {
        // ---- collision, non-adjacent: prune + compact worklist + dense pass ----
        int r = id - 216;
        int pi2 = r >> 1, dir = r & 1;
        pairIdx = 24 + pi2;
        int k = pi2, i1 = 0;
        while (i1 < NPATCH) {
            int cnt_ = (i1 == 0) ? 21 : (22 - i1);
            if (k < cnt_) break;
            k -= cnt_; ++i1;
        }
        int i2 = i1 + 2 + k;
        bool mask = false;
        for (int bb = 0; bb < NB; ++bb) {
            const float* B1 = bbF + (bb * NPATCH + i1) * 6;
            const float* B2 = bbF + (bb * NPATCH + i2) * 6;
            bool it = (B1[3] >= B2[0]) && (B2[3] >= B1[0]) &&
                      (B1[4] >= B2[1]) && (B2[4] >= B1[1]) &&
                      (B1[5] >= B2[2]) && (B2[5] >= B1[2]);
            mask |= it;
        }
        if (!mask) return;
        int ip_pts = dir ? i2 : i1;
        int ip_tri = dir ? i1 : i2;
        if (tid < 64) {
            const float* gp = grid + ((size_t)(b * NPATCH + ip_pts) * 64 + tid) * 3;
            Pts[tid] = make_float4(gp[0], gp[1], gp[2], 0.0f);
        } else if (tid < 128) {
            int q = tid - 64;
            const float* gq = grid + ((size_t)(b * NPATCH + ip_tri) * 64 + q) * 3;
            smem[q] = make_float4(gq[0], gq[1], gq[2], 0.0f);
        } else if (tid < 226) {
            int t = tid - 128;
            Sph[t] = TSg[(size_t)(b * NPATCH + ip_tri) * 98 + t];
        }
        if (tid == 0) cnt = 0;
        __syncthreads();
        int pt = tid & 63;
        float4 P = Pts[pt];
        float px = P.x, py = P.y, pz = P.z;
        float ub = 1e30f;
        int o0 = (tid >> 6) * 16;
        for (int q = o0; q < o0 + 16; ++q) {
            float4 Q = smem[q];
            float dx = px - Q.x, dy = py - Q.y, dz = pz - Q.z;
            ub = fminf(ub, dx * dx + dy * dy + dz * dz);
        }
        for (int o = 32; o > 0; o >>= 1) ub = fminf(ub, __shfl_xor(ub, o));
        if ((tid & 63) == 0) sred[tid >> 6] = ub;
        __syncthreads();
        ub = fminf(fminf(sred[0], sred[1]), fminf(sred[2], sred[3]));
        float sB = fminf(sqrtf(ub) + 1e-4f, PRUNE_MARGIN);
        best = ub;
        int lane = tid & 63;
        int wtri = tid >> 6;
        for (int t = wtri; t < 98; t += 4) {
            float4 S = Sph[t];
            float dx = px - S.x, dy = py - S.y, dz = pz - S.z;
            float lb = dx * dx + dy * dy + dz * dz;
            float thr = sB + S.w;
            bool pred = (lb <= thr * thr);
            unsigned long long mb = __ballot(pred);
            if (mb != 0ull) {
                int wbase;
                if (lane == 0) wbase = atomicAdd(&cnt, __popcll(mb));
                wbase = __shfl(wbase, 0);
                if (pred) {
                    int off = __popcll(mb & ((1ull << lane) - 1ull));
                    wl[wbase + off] = (unsigned short)((pt << 7) | t);
                }
            }
        }
        __syncthreads();
        int n = cnt;
        const float4* TD = TDg + (size_t)(b * NPATCH + ip_tri) * 98 * 4;
        for (int i = tid; i < n; i += 256) {
            int w = wl[i];
            int ppt = w >> 7, t = w & 127;
            float4 PP = Pts[ppt];
            best = fminf(best, ptTriSqDistP(PP.x, PP.y, PP.z, TD + t * 4));
        }
        __syncthreads();
    }

    for (int o = 32; o > 0; o >>= 1) best = fminf(best, __shfl_down(best, o));
    if ((tid & 63) == 0) sred[tid >> 6] = best;
    __syncthreads();
    if (tid == 0) {
        float d2 = fminf(fminf(sred[0], sred[1]), fminf(sred[2], sred[3]));
        atomicMin(&pairmin[b * 276 + pairIdx], encodeFloat(d2));
    }
}

// ---------- argmin recovery: one wave per query ----------
__global__ __launch_bounds__(256) void k_argmin(const float* __restrict__ target,
                                                const float* __restrict__ points,
                                                const float* __restrict__ pa,
                                                const float* __restrict__ pb,
                                                unsigned long long* __restrict__ best_a,
                                                unsigned long long* __restrict__ best_b) {
    int w = blockIdx.x * 4 + (threadIdx.x >> 6);
    int lane = threadIdx.x & 63;
    if (w < 24576) {
        int b = w / NPTS, qi = w - b * NPTS;
        float v = (lane < 32) ? pa[((size_t)(b * 32 + lane)) * NPTS + qi] : 1e30f;
        unsigned long long key = ((unsigned long long)encodeFloat(v) << 32) | (unsigned)lane;
        key = waveMinU64(key);
        int minch = (int)(key & 0xffffffffu);
        int base = minch * 128;
        const float* pp = points + ((size_t)b * NPTS + qi) * 3;
        float px = pp[0], py = pp[1], pz = pp[2];
        const float* tb0 = target + (size_t)b * MT * 6;
        unsigned long long bk = 0xFFFFFFFFFFFFFFFFull;
#pragma unroll
        for (int rr = 0; rr < 2; ++rr) {
            int k = base + lane + rr * 64;
            const float* tq = tb0 + (size_t)k * 6;
            float x = tq[0], y = tq[1], z = tq[2];
            float hw = 0.5f * (x * x + y * y + z * z);
            float s = fmaf(-px, x, fmaf(-py, y, fmaf(-pz, z, hw)));
            unsigned long long kk = ((unsigned long long)encodeFloat(s) << 32) | (unsigned)k;
            bk = (kk < bk) ? kk : bk;
        }
        bk = waveMinU64(bk);
        if (lane == 0) best_a[(size_t)b * NPTS + qi] = bk;
    } else {
        int idx = w - 24576;
        int b = idx / MT, mt = idx - b * MT;
        float v = (lane < 48) ? pb[((size_t)(b * 48 + lane)) * MT + mt] : 1e30f;
        unsigned long long key = ((unsigned long long)encodeFloat(v) << 32) | (unsigned)lane;
        key = waveMinU64(key);
        int minch = (int)(key & 0xffffffffu);
        int base = minch * 128;
        const float* tq = target + (size_t)(b * MT + mt) * 6;
        float tx = tq[0], ty = tq[1], tz = tq[2];
        const float* pt0 = points + (size_t)b * NPTS * 3;
        unsigned long long bk = 0xFFFFFFFFFFFFFFFFull;
#pragma unroll
        for (int rr = 0; rr < 2; ++rr) {
            int k = base + lane + rr * 64;
            const float* pp2 = pt0 + (size_t)k * 3;
            float x = pp2[0], y = pp2[1], z = pp2[2];
            float hw = 0.5f * (x * x + y * y + z * z);
            float s = fmaf(-tx, x, fmaf(-ty, y, fmaf(-tz, z, hw)));
            unsigned long long kk = ((unsigned long long)encodeFloat(s) << 32) | (unsigned)k;
            bk = (kk < bk) ? kk : bk;
        }
        bk = waveMinU64(bk);
        if (lane == 0) best_b[(size_t)b * MT + mt] = bk;
    }
}

// ---------- finalize A + B + fused finish (last of 160 blocks) ----------
__global__ __launch_bounds__(256) void k_final(const float* __restrict__ points,
                                               const float* __restrict__ normals,
                                               const float* __restrict__ target,
                                               const float* __restrict__ mtds,
                                               const float* __restrict__ st,
                                               const float* __restrict__ tmpl,
                                               const unsigned long long* __restrict__ best_a,
                                               const unsigned long long* __restrict__ best_b,
                                               float* __restrict__ acc,
                                               unsigned* __restrict__ pairmin,
                                               float* __restrict__ out) {
    __shared__ float finred[4];
    __shared__ int lastFlag;
    int id = blockIdx.x, b = blockIdx.y;
    if (id < 24) {
        int p = id;
        int m = threadIdx.x;
        int bp = b * NPATCH + p;
        const float* pp = points + (size_t)(bp * MPTS + m) * 3;
        float px = pp[0], py = pp[1], pz = pp[2];
        float pn = px * px + py * py + pz * pz;
        const float* nr = normals + (size_t)(bp * MPTS + m) * 3;
        float nx = nr[0], ny = nr[1], nz = nr[2];
        float w = mtds[bp * MPTS + m];
        float s = st[2 * m], t = st[2 * m + 1];
        unsigned long long pk = best_a[(size_t)b * NPTS + p * MPTS + m];
        float ca = fmaf(2.0f, decodeFloat((unsigned)(pk >> 32)), pn);
        int ia = (int)(pk & 0xffffffffu);
        const float* tq = target + (size_t)(b * MT + ia) * 6 + 3;
        float dx = nx - tq[0], dy = ny - tq[1], dz = nz - tq[2];
        float na = dx * dx + dy * dy + dz * dz;
        const float* tm = tmpl + (size_t)(p * MPTS + m) * 3;
        float ex = tm[0] - nx, ey = tm[1] - ny, ez = tm[2] - nz;
        float tnl = ex * ex + ey * ey + ez * ez;

        float vals[18];
        vals[0] = w * ca; vals[1] = w * na; vals[2] = w; vals[3] = w * tnl;
        vals[4] = s * px; vals[5] = s * py; vals[6] = s * pz;
        vals[7] = t * px; vals[8] = t * py; vals[9] = t * pz;
        vals[10] = px; vals[11] = py; vals[12] = pz;
        vals[13] = s * s; vals[14] = s * t; vals[15] = s; vals[16] = t * t; vals[17] = t;

        __shared__ float scratch[4 * 18];
        __shared__ float red[18];
        blockReduceSumN<18>(vals, red, scratch);

        __shared__ float sol[9];
        __shared__ float smtd_sh;
        if (threadIdx.x == 0) {
            float a00 = red[13], a01 = red[14], a02 = red[15];
            float a11 = red[16], a12 = red[17], a22 = 256.0f;
            float c00 = a11 * a22 - a12 * a12;
            float c01 = a02 * a12 - a01 * a22;
            float c02 = a01 * a12 - a02 * a11;
            float det = a00 * c00 + a01 * c01 + a02 * c02;
            float idet = 1.0f / det;
            float i00 = c00 * idet, i01 = c01 * idet, i02 = c02 * idet;
            float i11 = (a00 * a22 - a02 * a02) * idet;
            float i12 = (a01 * a02 - a00 * a12) * idet;
            float i22 = (a00 * a11 - a01 * a01) * idet;
#pragma unroll
            for (int c = 0; c < 3; ++c) {
                float b0 = red[4 + c], b1 = red[7 + c], b2 = red[10 + c];
                sol[0 * 3 + c] = i00 * b0 + i01 * b1 + i02 * b2;
                sol[1 * 3 + c] = i01 * b0 + i11 * b1 + i12 * b2;
                sol[2 * 3 + c] = i02 * b0 + i12 * b1 + i22 * b2;
            }
            smtd_sh = red[2];
            atomicAdd(&acc[0 + b], red[0]);
            atomicAdd(&acc[4 + b], red[1]);
            atomicAdd(&acc[8 + b], red[2]);
            atomicAdd(&acc[20], red[3] / red[2]);
        }
        __syncthreads();
        float rx = px - (s * sol[0] + t * sol[3] + sol[6]);
        float ry = py - (s * sol[1] + t * sol[4] + sol[7]);
        float rz = pz - (s * sol[2] + t * sol[5] + sol[8]);
        float v2 = w * (rx * rx + ry * ry + rz * rz);
        for (int o = 32; o > 0; o >>= 1) v2 += __shfl_down(v2, o);
        __shared__ float s2[4];
        if ((threadIdx.x & 63) == 0) s2[threadIdx.x >> 6] = v2;
        __syncthreads();
        if (threadIdx.x == 0)
            atomicAdd(&acc[21], (s2[0] + s2[1] + s2[2] + s2[3]) / smtd_sh);
    } else {
        int mc = id - 24;
        int mt = mc * 256 + threadIdx.x;
        const float* tq = target + (size_t)(b * MT + mt) * 6;
        float tx = tq[0], ty = tq[1], tz = tq[2];
        float tn2 = tx * tx + ty * ty + tz * tz;
        unsigned long long pk = best_b[(size_t)b * MT + mt];
        float cb = fmaf(2.0f, decodeFloat((unsigned)(pk >> 32)), tn2);
        int ib = (int)(pk & 0xffffffffu);
        const float* nr = normals + (size_t)(b * NPTS + ib) * 3;
        float dx = tq[3] - nr[0], dy = tq[4] - nr[1], dz = tq[5] - nr[2];
        float nb = dx * dx + dy * dy + dz * dz;
        float vals[2] = {cb, nb};
        __shared__ float scratchB[4 * 2];
        __shared__ float redB[2];
        blockReduceSumN<2>(vals, redB, scratchB);
        if (threadIdx.x == 0) {
            atomicAdd(&acc[12 + b], redB[0]);
            atomicAdd(&acc[16 + b], redB[1]);
        }
    }

    // ---- completion-counter fused finish (verified correct in R11) ----
    __syncthreads();
    if (threadIdx.x == 0) {
        __threadfence();
        unsigned done = atomicAdd((unsigned*)acc + 31, 1u) + 1u;
        lastFlag = (done == 160u) ? 1 : 0;
    }
    __syncthreads();
    if (!lastFlag) return;
    __threadfence();
    int tid = threadIdx.x;
    float s = 0.0f;
    for (int idx = tid; idx < 4 * 276; idx += 256) {
        unsigned key = atomicOr(&pairmin[idx], 0u);
        if (key != 0xFFFFFFFFu) {
            float d2 = decodeFloat(key);
            s += expf(-(d2 + 1e-12f) * SIGMA2INV);
        }
    }
    for (int o = 32; o > 0; o >>= 1) s += __shfl_down(s, o);
    if ((tid & 63) == 0) finred[tid >> 6] = s;
    __syncthreads();
    if (tid == 0) {
        float col = (finred[0] + finred[1] + finred[2] + finred[3]) * 0.25f;
        float ch = 0.0f, no = 0.0f;
        for (int bb = 0; bb < NB; ++bb) {
            float sa = atomicAdd(&acc[0 + bb], 0.0f);
            float sna = atomicAdd(&acc[4 + bb], 0.0f);
            float sw = atomicAdd(&acc[8 + bb], 0.0f);
            float scb = atomicAdd(&acc[12 + bb], 0.0f);
            float snb = atomicAdd(&acc[16 + bb], 0.0f);
            ch += sa / sw + scb / (float)MT;
            no += sna / sw + snb / (float)MT;
        }
        ch = ch * 0.25f * 0.5f;
        no = no * 0.25f * 0.5f;
        float tpl = atomicAdd(&acc[20], 0.0f) / 96.0f;
        float pl = atomicAdd(&acc[21], 0.0f) / 96.0f;
        float loss = ch + no + 0.01f * col + pl + tpl;
        out[0] = loss;
        out[1] = ch;
        out[2] = no;
        out[3] = col;
        out[4] = pl;
        out[5] = tpl;
        out[6] = 0.0f;
    }
}

// ---------- launch ----------
extern "C" void kernel_launch(void* const* d_in, const int* in_sizes, int n_in,
                              void* d_out, int out_size, void* d_ws, size_t ws_size,
                              hipStream_t stream) {
    (void)in_sizes; (void)n_in; (void)out_size; (void)ws_size;
    const float* target = (const float*)d_in[0];
    const float* patches = (const float*)d_in[1];
    const float* points = (const float*)d_in[2];
    const float* normals = (const float*)d_in[3];
    const float* mtds = (const float*)d_in[4];
    const float* st = (const float*)d_in[5];
    const float* tmpl = (const float*)d_in[6];
    float* out = (float*)d_out;
    char* ws = (char*)d_ws;

    float* grid = (float*)(ws + 0);                      //  73728
    float* bbF = (float*)(ws + 73728);                   //   2304
    float* bbE = (float*)(ws + 76032);                   //   2304
    unsigned* pairmin = (unsigned*)(ws + 78336);         //   4416
    float* acc = (float*)(ws + 82752);                   //    128 (incl. completion ctr @ [31])
    float4* TDg = (float4*)(ws + 82880);                 // 602112 -> 684992
    float4* TSg = (float4*)(ws + 684992);                // 150528 -> 835520
    float* pa = (float*)(ws + 835520);                   // 3145728 -> 3981248
    float* pb = (float*)(ws + 3981248);                  // 3145728 -> 7126976
    unsigned long long* best_a = (unsigned long long*)(ws + 7126976);  // 196608 -> 7323584
    unsigned long long* best_b = (unsigned long long*)(ws + 7323584);  // 131072 -> 7454656

    k_coons_tri<<<dim3(NB * NPATCH), dim3(128), 0, stream>>>(patches, grid, bbF, bbE,
                                                             TDg, TSg, pairmin, acc);
    k_mega<<<dim3(2880), dim3(256), 0, stream>>>(target, points, grid, TDg, TSg,
                                                 bbF, bbE, pa, pb, pairmin);
    k_argmin<<<dim3(10240), dim3(256), 0, stream>>>(target, points, pa, pb, best_a, best_b);
    k_final<<<dim3(40, NB), dim3(256), 0, stream>>>(points, normals, target, mtds, st,
                                                    tmpl, best_a, best_b, acc, pairmin, out);
}

// Round 15
// 71.325 us; speedup vs baseline: 1.1253x; 1.1253x over previous
//
#include <hip/hip_runtime.h>
#include <math.h>

#define NPATCH 24
#define NB 4
#define MPTS 256
#define MT 4096
#define NPTS (NPATCH*MPTS)   // 6144
#define GRIDPTS 64
#define SIGMA2INV 100.0f
#define PRUNE_MARGIN 0.45f   // exp(-100*0.45^2) ~ 2e-9, negligible vs threshold

// ---------- helpers ----------

__device__ inline unsigned encodeFloat(float f) {
    unsigned u = __float_as_uint(f);
    return (u & 0x80000000u) ? ~u : (u | 0x80000000u);
}
__device__ inline float decodeFloat(unsigned e) {
    return __uint_as_float((e & 0x80000000u) ? (e ^ 0x80000000u) : ~e);
}

__device__ inline unsigned long long waveMinU64(unsigned long long k) {
    for (int o = 32; o > 0; o >>= 1) {
        unsigned long long other = __shfl_xor(k, o);
        k = (other < k) ? other : k;
    }
    return k;
}

template<int NV>
__device__ inline void blockReduceSumN(const float* vals, float* out, float* scratch) {
    int wid = threadIdx.x >> 6, lane = threadIdx.x & 63;
#pragma unroll
    for (int i = 0; i < NV; ++i) {
        float v = vals[i];
        for (int o = 32; o > 0; o >>= 1) v += __shfl_down(v, o);
        if (lane == 0) scratch[wid * NV + i] = v;
    }
    __syncthreads();
    if (threadIdx.x < NV)
        out[threadIdx.x] = scratch[0 * NV + threadIdx.x] + scratch[1 * NV + threadIdx.x] +
                           scratch[2 * NV + threadIdx.x] + scratch[3 * NV + threadIdx.x];
    __syncthreads();
}

__device__ inline float clamp01f(float x) { return fminf(fmaxf(x, 0.0f), 1.0f); }
__device__ inline float safercp(float x) {
    float s = fabsf(x) < 1e-12f ? 1e-12f : x;
    return __builtin_amdgcn_rcpf(s);
}

// point-vs-tri sq distance using precomputed tri data (4 float4 per tri)
__device__ inline float ptTriSqDistP(float px, float py, float pz, const float4* T) {
    float4 f0 = T[0], f1 = T[1], f2 = T[2], f3 = T[3];
    float ax = f0.x, ay = f0.y, az = f0.z;
    float abx = f1.x, aby = f1.y, abz = f1.z;
    float acx = f2.x, acy = f2.y, acz = f2.z;
    float abp = abx * px + aby * py + abz * pz;
    float acp = acx * px + acy * py + acz * pz;
    float d1 = abp - f0.w;
    float d2 = acp - f1.w;
    float d3 = abp - f2.w;
    float d4 = acp - f3.x;
    float d5 = abp - f3.y;
    float d6 = acp - f3.z;
    float vc = d1 * d4 - d3 * d2;
    float vb = d5 * d2 - d1 * d6;
    float va = d3 * d6 - d5 * d4;
    float t_ab = clamp01f(d1 * safercp(d1 - d3));
    float t_ac = clamp01f(d2 * safercp(d2 - d6));
    float t_bc = clamp01f((d4 - d3) * safercp((d4 - d3) + (d5 - d6)));
    float rden = safercp(va + vb + vc);
    float v = vb * rden, w = vc * rden;
    float clx = ax + abx * v + acx * w;
    float cly = ay + aby * v + acy * w;
    float clz = az + abz * v + acz * w;
    if (va <= 0.0f && (d4 - d3) >= 0.0f && (d5 - d6) >= 0.0f) {
        clx = (ax + abx) + (acx - abx) * t_bc;
        cly = (ay + aby) + (acy - aby) * t_bc;
        clz = (az + abz) + (acz - abz) * t_bc;
    }
    if (vb <= 0.0f && d2 >= 0.0f && d6 <= 0.0f) {
        clx = ax + acx * t_ac; cly = ay + acy * t_ac; clz = az + acz * t_ac;
    }
    if (d6 >= 0.0f && d5 <= d6) { clx = ax + acx; cly = ay + acy; clz = az + acz; }
    if (vc <= 0.0f && d1 >= 0.0f && d3 <= 0.0f) {
        clx = ax + abx * t_ab; cly = ay + aby * t_ab; clz = az + abz * t_ab;
    }
    if (d3 >= 0.0f && d4 <= d3) { clx = ax + abx; cly = ay + aby; clz = az + abz; }
    if (d1 <= 0.0f && d2 <= 0.0f) { clx = ax; cly = ay; clz = az; }
    float dx = px - clx, dy = py - cly, dz = pz - clz;
    return dx * dx + dy * dy + dz * dz;
}

// ---------- kernel 1: Coons sampling + bboxes + tri data + ws init (fused) ----------
__global__ __launch_bounds__(128) void k_coons_tri(const float* __restrict__ patches,
                                                   float* __restrict__ grid,
                                                   float* __restrict__ bbF,
                                                   float* __restrict__ bbE,
                                                   float4* __restrict__ TDg,
                                                   float4* __restrict__ TSg,
                                                   unsigned* __restrict__ pairmin,
                                                   float* __restrict__ acc) {
    __shared__ float Pl[192];
    int bp = blockIdx.x;
    int m = threadIdx.x;
    if (bp == 0) {
        for (int i = m; i < 1104; i += 128) pairmin[i] = 0xFFFFFFFFu;
        if (m < 32) acc[m] = 0.0f;
    }
    if (m < 64) {
        int i = m >> 3, j = m & 7;
        float s = (i == 7) ? 1.0f : (float)i * (1.0f / 7.0f);
        float t = (j == 7) ? 1.0f : (float)j * (1.0f / 7.0f);
        const float* cp = patches + bp * 36;
        float bs[4], bt[4], bs1[4], bt1[4];
        {
            float u, vv;
            u = s; vv = 1.0f - u; bs[0] = vv * vv * vv; bs[1] = 3.f * u * vv * vv; bs[2] = 3.f * u * u * vv; bs[3] = u * u * u;
            u = t; vv = 1.0f - u; bt[0] = vv * vv * vv; bt[1] = 3.f * u * vv * vv; bt[2] = 3.f * u * u * vv; bt[3] = u * u * u;
            u = 1.0f - s; vv = 1.0f - u; bs1[0] = vv * vv * vv; bs1[1] = 3.f * u * vv * vv; bs1[2] = 3.f * u * u * vv; bs1[3] = u * u * u;
            u = 1.0f - t; vv = 1.0f - u; bt1[0] = vv * vv * vv; bt1[1] = 3.f * u * vv * vv; bt1[2] = 3.f * u * u * vv; bt1[3] = u * u * u;
        }
        float g[3];
#pragma unroll
        for (int c = 0; c < 3; ++c) {
            float cb = bs[0] * cp[0 * 3 + c] + bs[1] * cp[1 * 3 + c] + bs[2] * cp[2 * 3 + c] + bs[3] * cp[3 * 3 + c];
            float cr = bt[0] * cp[3 * 3 + c] + bt[1] * cp[4 * 3 + c] + bt[2] * cp[5 * 3 + c] + bt[3] * cp[6 * 3 + c];
            float ct = bs1[0] * cp[6 * 3 + c] + bs1[1] * cp[7 * 3 + c] + bs1[2] * cp[8 * 3 + c] + bs1[3] * cp[9 * 3 + c];
            float cl = bt1[0] * cp[9 * 3 + c] + bt1[1] * cp[10 * 3 + c] + bt1[2] * cp[11 * 3 + c] + bt1[3] * cp[0 * 3 + c];
            float P00 = cp[0 * 3 + c], P10 = cp[3 * 3 + c], P11 = cp[6 * 3 + c], P01 = cp[9 * 3 + c];
            float ruled = (1.0f - t) * cb + t * ct + (1.0f - s) * cl + s * cr;
            float bil = (1.0f - s) * (1.0f - t) * P00 + s * (1.0f - t) * P10 + s * t * P11 + (1.0f - s) * t * P01;
            g[c] = ruled - bil;
            grid[(bp * GRIDPTS + m) * 3 + c] = g[c];
            Pl[m * 3 + c] = g[c];
        }
        float mnF[3], mxF[3], mnE[3], mxE[3];
        bool edge = (m >= 56);
#pragma unroll
        for (int c = 0; c < 3; ++c) {
            mnF[c] = g[c]; mxF[c] = g[c];
            mnE[c] = edge ? g[c] : 1e30f;
            mxE[c] = edge ? g[c] : -1e30f;
        }
        for (int o = 32; o > 0; o >>= 1) {
#pragma unroll
            for (int c = 0; c < 3; ++c) {
                mnF[c] = fminf(mnF[c], __shfl_down(mnF[c], o));
                mxF[c] = fmaxf(mxF[c], __shfl_down(mxF[c], o));
                mnE[c] = fminf(mnE[c], __shfl_down(mnE[c], o));
                mxE[c] = fmaxf(mxE[c], __shfl_down(mxE[c], o));
            }
        }
        if (m == 0) {
#pragma unroll
            for (int c = 0; c < 3; ++c) {
                bbF[bp * 6 + c] = mnF[c]; bbF[bp * 6 + 3 + c] = mxF[c];
                bbE[bp * 6 + c] = mnE[c]; bbE[bp * 6 + 3 + c] = mxE[c];
            }
        }
    }
    __syncthreads();
    int t = m;
    if (t < 98) {
        int cell = t >> 1, ii = cell / 7, jj = cell - ii * 7;
        int v00 = ii * 8 + jj;
        int va, vb, vc;
        if (t & 1) { va = v00 + 8; vb = v00 + 9; vc = v00 + 1; }
        else       { va = v00;     vb = v00 + 8; vc = v00 + 1; }
        float ax = Pl[va * 3], ay = Pl[va * 3 + 1], az = Pl[va * 3 + 2];
        float bx = Pl[vb * 3], by = Pl[vb * 3 + 1], bz = Pl[vb * 3 + 2];
        float cx = Pl[vc * 3], cy = Pl[vc * 3 + 1], cz = Pl[vc * 3 + 2];
        float abx = bx - ax, aby = by - ay, abz = bz - az;
        float acx = cx - ax, acy = cy - ay, acz = cz - az;
        float ab_a = abx * ax + aby * ay + abz * az;
        float ac_a = acx * ax + acy * ay + acz * az;
        float ab_b = abx * bx + aby * by + abz * bz;
        float ac_b = acx * bx + acy * by + acz * bz;
        float ab_c = abx * cx + aby * cy + abz * cz;
        float ac_c = acx * cx + acy * cy + acz * cz;
        float4* dst = TDg + ((size_t)bp * 98 + t) * 4;
        dst[0] = make_float4(ax, ay, az, ab_a);
        dst[1] = make_float4(abx, aby, abz, ac_a);
        dst[2] = make_float4(acx, acy, acz, ab_b);
        dst[3] = make_float4(ac_b, ab_c, ac_c, 0.0f);
        float gx = (ax + bx + cx) * (1.0f / 3.0f);
        float gy = (ay + by + cy) * (1.0f / 3.0f);
        float gz = (az + bz + cz) * (1.0f / 3.0f);
        float ra = (ax - gx) * (ax - gx) + (ay - gy) * (ay - gy) + (az - gz) * (az - gz);
        float rb = (bx - gx) * (bx - gx) + (by - gy) * (by - gy) + (bz - gz) * (bz - gz);
        float rc = (cx - gx) * (cx - gx) + (cy - gy) * (cy - gy) + (cz - gz) * (cz - gz);
        float r = sqrtf(fmaxf(ra, fmaxf(rb, rc)));
        TSg[(size_t)bp * 98 + t] = make_float4(gx, gy, gz, r);
    }
}

// ---------- mega kernel ----------
// ids per b (gridDim.x = 720), LONG chamfer blocks FIRST (LPT packing):
//  [0,96):   chamfer A  qb=id>>5 (3 query-blocks of 2048 pts), ch=id&31 (32 target-chunks of 128)
//  [96,192): chamfer B  rel=id-96: qb=rel/48 (2 query-blocks of 2048 tgts), ch=rel%48 (48 point-chunks of 128)
//  [192,216): collision adjacent
//  [216,720): collision non-adjacent, r=id-216: pair=r>>1, dir=r&1
__global__ __launch_bounds__(256) void k_mega(const float* __restrict__ target,
                                              const float* __restrict__ points,
                                              const float* __restrict__ grid,
                                              const float4* __restrict__ TDg,
                                              const float4* __restrict__ TSg,
                                              const float* __restrict__ bbF,
                                              const float* __restrict__ bbE,
                                              float* __restrict__ pa,
                                              float* __restrict__ pb,
                                              unsigned* __restrict__ pairmin) {
    __shared__ float4 smem[128];
    __shared__ float4 Pts[64];
    __shared__ float4 Sph[98];
    __shared__ unsigned short wl[6272];
    __shared__ int cnt;
    __shared__ float sred[4];
    int id = blockIdx.x;
    int b = blockIdx.y;
    int tid = threadIdx.x;

    if (id < 192) {
        bool isA = (id < 96);
        int qbase, ch;
        float qx0, qy0, qz0, qx1, qy1, qz1, qx2, qy2, qz2, qx3, qy3, qz3;
        float qx4, qy4, qz4, qx5, qy5, qz5, qx6, qy6, qz6, qx7, qy7, qz7;
        if (isA) {
            int qb = id >> 5; ch = id & 31;
            qbase = qb * 2048 + tid * 8;
            int chbase = ch * 128;
            if (tid < 128) {
                const float* tp = target + (size_t)(b * MT + chbase + tid) * 6;
                float x = tp[0], y = tp[1], z = tp[2];
                smem[tid] = make_float4(x, y, z, 0.5f * (x * x + y * y + z * z));
            }
            const float4* pf = (const float4*)(points + ((size_t)b * NPTS + qbase) * 3);
            float4 v0 = pf[0], v1 = pf[1], v2 = pf[2], v3 = pf[3], v4 = pf[4], v5 = pf[5];
            qx0 = v0.x; qy0 = v0.y; qz0 = v0.z;
            qx1 = v0.w; qy1 = v1.x; qz1 = v1.y;
            qx2 = v1.z; qy2 = v1.w; qz2 = v2.x;
            qx3 = v2.y; qy3 = v2.z; qz3 = v2.w;
            qx4 = v3.x; qy4 = v3.y; qz4 = v3.z;
            qx5 = v3.w; qy5 = v4.x; qz5 = v4.y;
            qx6 = v4.z; qy6 = v4.w; qz6 = v5.x;
            qx7 = v5.y; qy7 = v5.z; qz7 = v5.w;
        } else {
            int rel = id - 96;
            int qb = rel / 48; ch = rel - qb * 48;
            qbase = qb * 2048 + tid * 8;
            int chbase = ch * 128;
            if (tid < 128) {
                const float* pp = points + (size_t)(b * NPTS + chbase + tid) * 3;
                float x = pp[0], y = pp[1], z = pp[2];
                smem[tid] = make_float4(x, y, z, 0.5f * (x * x + y * y + z * z));
            }
            const float* tf = target + (size_t)(b * MT + qbase) * 6;
            float2 a0 = *(const float2*)(tf + 0);  float z0 = tf[2];
            float2 a1 = *(const float2*)(tf + 6);  float z1 = tf[8];
            float2 a2 = *(const float2*)(tf + 12); float z2 = tf[14];
            float2 a3 = *(const float2*)(tf + 18); float z3 = tf[20];
            float2 a4 = *(const float2*)(tf + 24); float z4 = tf[26];
            float2 a5 = *(const float2*)(tf + 30); float z5 = tf[32];
            float2 a6 = *(const float2*)(tf + 36); float z6 = tf[38];
            float2 a7 = *(const float2*)(tf + 42); float z7 = tf[44];
            qx0 = a0.x; qy0 = a0.y; qz0 = z0;
            qx1 = a1.x; qy1 = a1.y; qz1 = z1;
            qx2 = a2.x; qy2 = a2.y; qz2 = z2;
            qx3 = a3.x; qy3 = a3.y; qz3 = z3;
            qx4 = a4.x; qy4 = a4.y; qz4 = z4;
            qx5 = a5.x; qy5 = a5.y; qz5 = z5;
            qx6 = a6.x; qy6 = a6.y; qz6 = z6;
            qx7 = a7.x; qy7 = a7.y; qz7 = z7;
        }
        __syncthreads();
        float sc0 = 1e30f, sc1 = 1e30f, sc2 = 1e30f, sc3 = 1e30f;
        float sc4 = 1e30f, sc5 = 1e30f, sc6 = 1e30f, sc7 = 1e30f;
#pragma unroll 8
        for (int k = 0; k < 128; ++k) {
            float4 T = smem[k];
            sc0 = fminf(sc0, fmaf(-qx0, T.x, fmaf(-qy0, T.y, fmaf(-qz0, T.z, T.w))));
            sc1 = fminf(sc1, fmaf(-qx1, T.x, fmaf(-qy1, T.y, fmaf(-qz1, T.z, T.w))));
            sc2 = fminf(sc2, fmaf(-qx2, T.x, fmaf(-qy2, T.y, fmaf(-qz2, T.z, T.w))));
            sc3 = fminf(sc3, fmaf(-qx3, T.x, fmaf(-qy3, T.y, fmaf(-qz3, T.z, T.w))));
            sc4 = fminf(sc4, fmaf(-qx4, T.x, fmaf(-qy4, T.y, fmaf(-qz4, T.z, T.w))));
            sc5 = fminf(sc5, fmaf(-qx5, T.x, fmaf(-qy5, T.y, fmaf(-qz5, T.z, T.w))));
            sc6 = fminf(sc6, fmaf(-qx6, T.x, fmaf(-qy6, T.y, fmaf(-qz6, T.z, T.w))));
            sc7 = fminf(sc7, fmaf(-qx7, T.x, fmaf(-qy7, T.y, fmaf(-qz7, T.z, T.w))));
        }
        float* dstp = isA ? (pa + ((size_t)(b * 32 + ch)) * NPTS + qbase)
                          : (pb + ((size_t)(b * 48 + ch)) * MT + qbase);
        *(float4*)(dstp) = make_float4(sc0, sc1, sc2, sc3);
        *(float4*)(dstp + 4) = make_float4(sc4, sc5, sc6, sc7);
        return;
    }

    float best = 1e30f;
    int pairIdx;

    if (id < 216) {
        // ---- collision, adjacent pair ----
        int pair = id - 192;
        pairIdx = pair;
        int i1 = pair, i2 = (pair + 1) % NPATCH;
        bool mask = false;
        for (int bb = 0; bb < NB; ++bb) {
            const float* B1 = bbE + (bb * NPATCH + i1) * 6;
            const float* B2 = bbF + (bb * NPATCH + i2) * 6;
            bool it = (B1[3] >= B2[0]) && (B2[3] >= B1[0]) &&
                      (B1[4] >= B2[1]) && (B2[4] >= B1[1]) &&
                      (B1[5] >= B2[2]) && (B2[5] >= B1[2]);
            mask |= it;
        }
        if (!mask) return;
        const float* P1 = grid + (size_t)(b * NPATCH + i1) * 192;
        const float* P2 = grid + (size_t)(b * NPATCH + i2) * 192;
        const float4* T1 = TDg + (size_t)(b * NPATCH + i1) * 98 * 4;
        const float4* T2 = TDg + (size_t)(b * NPATCH + i2) * 98 * 4;
        for (int tt = tid; tt < 1232; tt += 256) {
            const float4* T;
            float px, py, pz;
            if (tt < 784) {
                int ptI = tt / 98, tri = tt - ptI * 98;
                const float* gp = P1 + (56 + ptI) * 3;
                px = gp[0]; py = gp[1]; pz = gp[2];
                T = T2 + tri * 4;
            } else {
                int rr = tt - 784;
                int ptI = rr / 7, e = rr - ptI * 7;
                const float* gp = P2 + ptI * 3;
                px = gp[0]; py = gp[1]; pz = gp[2];
                T = T1 + (85 + 2 * e) * 4;
            }
            best = fminf(best, ptTriSqDistP(px, py, pz, T));
        }
    } else {
        // ---- collision, non-adjacent: prune + compact worklist + dense pass ----
        int r = id - 216;
        int pi2 = r >> 1, dir = r & 1;
        pairIdx = 24 + pi2;
        int k = pi2, i1 = 0;
        while (i1 < NPATCH) {
            int cnt_ = (i1 == 0) ? 21 : (22 - i1);
            if (k < cnt_) break;
            k -= cnt_; ++i1;
        }
        int i2 = i1 + 2 + k;
        bool mask = false;
        for (int bb = 0; bb < NB; ++bb) {
            const float* B1 = bbF + (bb * NPATCH + i1) * 6;
            const float* B2 = bbF + (bb * NPATCH + i2) * 6;
            bool it = (B1[3] >= B2[0]) && (B2[3] >= B1[0]) &&
                      (B1[4] >= B2[1]) && (B2[4] >= B1[1]) &&
                      (B1[5] >= B2[2]) && (B2[5] >= B1[2]);
            mask |= it;
        }
        if (!mask) return;
        int ip_pts = dir ? i2 : i1;
        int ip_tri = dir ? i1 : i2;
        if (tid < 64) {
            const float* gp = grid + ((size_t)(b * NPATCH + ip_pts) * 64 + tid) * 3;
            Pts[tid] = make_float4(gp[0], gp[1], gp[2], 0.0f);
        } else if (tid < 128) {
            int q = tid - 64;
            const float* gq = grid + ((size_t)(b * NPATCH + ip_tri) * 64 + q) * 3;
            smem[q] = make_float4(gq[0], gq[1], gq[2], 0.0f);
        } else if (tid < 226) {
            int t = tid - 128;
            Sph[t] = TSg[(size_t)(b * NPATCH + ip_tri) * 98 + t];
        }
        if (tid == 0) cnt = 0;
        __syncthreads();
        int pt = tid & 63;
        float4 P = Pts[pt];
        float px = P.x, py = P.y, pz = P.z;
        float ub = 1e30f;
        int o0 = (tid >> 6) * 16;
        for (int q = o0; q < o0 + 16; ++q) {
            float4 Q = smem[q];
            float dx = px - Q.x, dy = py - Q.y, dz = pz - Q.z;
            ub = fminf(ub, dx * dx + dy * dy + dz * dz);
        }
        for (int o = 32; o > 0; o >>= 1) ub = fminf(ub, __shfl_xor(ub, o));
        if ((tid & 63) == 0) sred[tid >> 6] = ub;
        __syncthreads();
        ub = fminf(fminf(sred[0], sred[1]), fminf(sred[2], sred[3]));
        float sB = fminf(sqrtf(ub) + 1e-4f, PRUNE_MARGIN);
        best = ub;
        int lane = tid & 63;
        int wtri = tid >> 6;
        for (int t = wtri; t < 98; t += 4) {
            float4 S = Sph[t];
            float dx = px - S.x, dy = py - S.y, dz = pz - S.z;
            float lb = dx * dx + dy * dy + dz * dz;
            float thr = sB + S.w;
            bool pred = (lb <= thr * thr);
            unsigned long long mb = __ballot(pred);
            if (mb != 0ull) {
                int wbase;
                if (lane == 0) wbase = atomicAdd(&cnt, __popcll(mb));
                wbase = __shfl(wbase, 0);
                if (pred) {
                    int off = __popcll(mb & ((1ull << lane) - 1ull));
                    wl[wbase + off] = (unsigned short)((pt << 7) | t);
                }
            }
        }
        __syncthreads();
        int n = cnt;
        const float4* TD = TDg + (size_t)(b * NPATCH + ip_tri) * 98 * 4;
        for (int i = tid; i < n; i += 256) {
            int w = wl[i];
            int ppt = w >> 7, t = w & 127;
            float4 PP = Pts[ppt];
            best = fminf(best, ptTriSqDistP(PP.x, PP.y, PP.z, TD + t * 4));
        }
        __syncthreads();
    }

    for (int o = 32; o > 0; o >>= 1) best = fminf(best, __shfl_down(best, o));
    if ((tid & 63) == 0) sred[tid >> 6] = best;
    __syncthreads();
    if (tid == 0) {
        float d2 = fminf(fminf(sred[0], sred[1]), fminf(sred[2], sred[3]));
        atomicMin(&pairmin[b * 276 + pairIdx], encodeFloat(d2));
    }
}

// ---------- argmin recovery: one wave per query ----------
__global__ __launch_bounds__(256) void k_argmin(const float* __restrict__ target,
                                                const float* __restrict__ points,
                                                const float* __restrict__ pa,
                                                const float* __restrict__ pb,
                                                unsigned long long* __restrict__ best_a,
                                                unsigned long long* __restrict__ best_b) {
    int w = blockIdx.x * 4 + (threadIdx.x >> 6);
    int lane = threadIdx.x & 63;
    if (w < 24576) {
        int b = w / NPTS, qi = w - b * NPTS;
        float v = (lane < 32) ? pa[((size_t)(b * 32 + lane)) * NPTS + qi] : 1e30f;
        unsigned long long key = ((unsigned long long)encodeFloat(v) << 32) | (unsigned)lane;
        key = waveMinU64(key);
        int minch = (int)(key & 0xffffffffu);
        int base = minch * 128;
        const float* pp = points + ((size_t)b * NPTS + qi) * 3;
        float px = pp[0], py = pp[1], pz = pp[2];
        const float* tb0 = target + (size_t)b * MT * 6;
        unsigned long long bk = 0xFFFFFFFFFFFFFFFFull;
#pragma unroll
        for (int rr = 0; rr < 2; ++rr) {
            int k = base + lane + rr * 64;
            const float* tq = tb0 + (size_t)k * 6;
            float x = tq[0], y = tq[1], z = tq[2];
            float hw = 0.5f * (x * x + y * y + z * z);
            float s = fmaf(-px, x, fmaf(-py, y, fmaf(-pz, z, hw)));
            unsigned long long kk = ((unsigned long long)encodeFloat(s) << 32) | (unsigned)k;
            bk = (kk < bk) ? kk : bk;
        }
        bk = waveMinU64(bk);
        if (lane == 0) best_a[(size_t)b * NPTS + qi] = bk;
    } else {
        int idx = w - 24576;
        int b = idx / MT, mt = idx - b * MT;
        float v = (lane < 48) ? pb[((size_t)(b * 48 + lane)) * MT + mt] : 1e30f;
        unsigned long long key = ((unsigned long long)encodeFloat(v) << 32) | (unsigned)lane;
        key = waveMinU64(key);
        int minch = (int)(key & 0xffffffffu);
        int base = minch * 128;
        const float* tq = target + (size_t)(b * MT + mt) * 6;
        float tx = tq[0], ty = tq[1], tz = tq[2];
        const float* pt0 = points + (size_t)b * NPTS * 3;
        unsigned long long bk = 0xFFFFFFFFFFFFFFFFull;
#pragma unroll
        for (int rr = 0; rr < 2; ++rr) {
            int k = base + lane + rr * 64;
            const float* pp2 = pt0 + (size_t)k * 3;
            float x = pp2[0], y = pp2[1], z = pp2[2];
            float hw = 0.5f * (x * x + y * y + z * z);
            float s = fmaf(-tx, x, fmaf(-ty, y, fmaf(-tz, z, hw)));
            unsigned long long kk = ((unsigned long long)encodeFloat(s) << 32) | (unsigned)k;
            bk = (kk < bk) ? kk : bk;
        }
        bk = waveMinU64(bk);
        if (lane == 0) best_b[(size_t)b * MT + mt] = bk;
    }
}

// ---------- finalize A (per (b,p)) + finalize B fused ----------
__global__ __launch_bounds__(256) void k_final(const float* __restrict__ points,
                                               const float* __restrict__ normals,
                                               const float* __restrict__ target,
                                               const float* __restrict__ mtds,
                                               const float* __restrict__ st,
                                               const float* __restrict__ tmpl,
                                               const unsigned long long* __restrict__ best_a,
                                               const unsigned long long* __restrict__ best_b,
                                               float* __restrict__ acc) {
    int id = blockIdx.x, b = blockIdx.y;
    if (id < 24) {
        int p = id;
        int m = threadIdx.x;
        int bp = b * NPATCH + p;
        const float* pp = points + (size_t)(bp * MPTS + m) * 3;
        float px = pp[0], py = pp[1], pz = pp[2];
        float pn = px * px + py * py + pz * pz;
        const float* nr = normals + (size_t)(bp * MPTS + m) * 3;
        float nx = nr[0], ny = nr[1], nz = nr[2];
        float w = mtds[bp * MPTS + m];
        float s = st[2 * m], t = st[2 * m + 1];
        unsigned long long pk = best_a[(size_t)b * NPTS + p * MPTS + m];
        float ca = fmaf(2.0f, decodeFloat((unsigned)(pk >> 32)), pn);
        int ia = (int)(pk & 0xffffffffu);
        const float* tq = target + (size_t)(b * MT + ia) * 6 + 3;
        float dx = nx - tq[0], dy = ny - tq[1], dz = nz - tq[2];
        float na = dx * dx + dy * dy + dz * dz;
        const float* tm = tmpl + (size_t)(p * MPTS + m) * 3;
        float ex = tm[0] - nx, ey = tm[1] - ny, ez = tm[2] - nz;
        float tnl = ex * ex + ey * ey + ez * ez;

        float vals[18];
        vals[0] = w * ca; vals[1] = w * na; vals[2] = w; vals[3] = w * tnl;
        vals[4] = s * px; vals[5] = s * py; vals[6] = s * pz;
        vals[7] = t * px; vals[8] = t * py; vals[9] = t * pz;
        vals[10] = px; vals[11] = py; vals[12] = pz;
        vals[13] = s * s; vals[14] = s * t; vals[15] = s; vals[16] = t * t; vals[17] = t;

        __shared__ float scratch[4 * 18];
        __shared__ float red[18];
        blockReduceSumN<18>(vals, red, scratch);

        __shared__ float sol[9];
        __shared__ float smtd_sh;
        if (threadIdx.x == 0) {
            float a00 = red[13], a01 = red[14], a02 = red[15];
            float a11 = red[16], a12 = red[17], a22 = 256.0f;
            float c00 = a11 * a22 - a12 * a12;
            float c01 = a02 * a12 - a01 * a22;
            float c02 = a01 * a12 - a02 * a11;
            float det = a00 * c00 + a01 * c01 + a02 * c02;
            float idet = 1.0f / det;
            float i00 = c00 * idet, i01 = c01 * idet, i02 = c02 * idet;
            float i11 = (a00 * a22 - a02 * a02) * idet;
            float i12 = (a01 * a02 - a00 * a12) * idet;
            float i22 = (a00 * a11 - a01 * a01) * idet;
#pragma unroll
            for (int c = 0; c < 3; ++c) {
                float b0 = red[4 + c], b1 = red[7 + c], b2 = red[10 + c];
                sol[0 * 3 + c] = i00 * b0 + i01 * b1 + i02 * b2;
                sol[1 * 3 + c] = i01 * b0 + i11 * b1 + i12 * b2;
                sol[2 * 3 + c] = i02 * b0 + i12 * b1 + i22 * b2;
            }
            smtd_sh = red[2];
            atomicAdd(&acc[0 + b], red[0]);
            atomicAdd(&acc[4 + b], red[1]);
            atomicAdd(&acc[8 + b], red[2]);
            atomicAdd(&acc[20], red[3] / red[2]);
        }
        __syncthreads();
        float rx = px - (s * sol[0] + t * sol[3] + sol[6]);
        float ry = py - (s * sol[1] + t * sol[4] + sol[7]);
        float rz = pz - (s * sol[2] + t * sol[5] + sol[8]);
        float v2 = w * (rx * rx + ry * ry + rz * rz);
        for (int o = 32; o > 0; o >>= 1) v2 += __shfl_down(v2, o);
        __shared__ float s2[4];
        if ((threadIdx.x & 63) == 0) s2[threadIdx.x >> 6] = v2;
        __syncthreads();
        if (threadIdx.x == 0)
            atomicAdd(&acc[21], (s2[0] + s2[1] + s2[2] + s2[3]) / smtd_sh);
    } else {
        int mc = id - 24;
        int mt = mc * 256 + threadIdx.x;
        const float* tq = target + (size_t)(b * MT + mt) * 6;
        float tx = tq[0], ty = tq[1], tz = tq[2];
        float tn2 = tx * tx + ty * ty + tz * tz;
        unsigned long long pk = best_b[(size_t)b * MT + mt];
        float cb = fmaf(2.0f, decodeFloat((unsigned)(pk >> 32)), tn2);
        int ib = (int)(pk & 0xffffffffu);
        const float* nr = normals + (size_t)(b * NPTS + ib) * 3;
        float dx = tq[3] - nr[0], dy = tq[4] - nr[1], dz = tq[5] - nr[2];
        float nb = dx * dx + dy * dy + dz * dz;
        float vals[2] = {cb, nb};
        __shared__ float scratchB[4 * 2];
        __shared__ float redB[2];
        blockReduceSumN<2>(vals, redB, scratchB);
        if (threadIdx.x == 0) {
            atomicAdd(&acc[12 + b], redB[0]);
            atomicAdd(&acc[16 + b], redB[1]);
        }
    }
}

// ---------- finish ----------
__global__ __launch_bounds__(256) void k_finish(const float* __restrict__ acc,
                                                const unsigned* __restrict__ pairmin,
                                                float* __restrict__ out) {
    int tid = threadIdx.x;
    float s = 0.0f;
    for (int idx = tid; idx < 4 * 276; idx += 256) {
        unsigned key = pairmin[idx];
        if (key != 0xFFFFFFFFu) {
            float d2 = decodeFloat(key);
            s += expf(-(d2 + 1e-12f) * SIGMA2INV);
        }
    }
    for (int o = 32; o > 0; o >>= 1) s += __shfl_down(s, o);
    __shared__ float sred[4];
    if ((tid & 63) == 0) sred[tid >> 6] = s;
    __syncthreads();
    if (tid == 0) {
        float col = (sred[0] + sred[1] + sred[2] + sred[3]) * 0.25f;
        float ch = 0.0f, no = 0.0f;
        for (int b = 0; b < NB; ++b) {
            float caw = acc[0 + b] / acc[8 + b];
            float naw = acc[4 + b] / acc[8 + b];
            float cbm = acc[12 + b] / (float)MT;
            float nbm = acc[16 + b] / (float)MT;
            ch += caw + cbm;
            no += naw + nbm;
        }
        ch = ch * 0.25f * 0.5f;
        no = no * 0.25f * 0.5f;
        float tpl = acc[20] / 96.0f;
        float pl = acc[21] / 96.0f;
        float loss = ch + no + 0.01f * col + pl + tpl;
        out[0] = loss;
        out[1] = ch;
        out[2] = no;
        out[3] = col;
        out[4] = pl;
        out[5] = tpl;
        out[6] = 0.0f;
    }
}

// ---------- launch ----------
extern "C" void kernel_launch(void* const* d_in, const int* in_sizes, int n_in,
                              void* d_out, int out_size, void* d_ws, size_t ws_size,
                              hipStream_t stream) {
    (void)in_sizes; (void)n_in; (void)out_size; (void)ws_size;
    const float* target = (const float*)d_in[0];
    const float* patches = (const float*)d_in[1];
    const float* points = (const float*)d_in[2];
    const float* normals = (const float*)d_in[3];
    const float* mtds = (const float*)d_in[4];
    const float* st = (const float*)d_in[5];
    const float* tmpl = (const float*)d_in[6];
    float* out = (float*)d_out;
    char* ws = (char*)d_ws;

    float* grid = (float*)(ws + 0);                      //  73728
    float* bbF = (float*)(ws + 73728);                   //   2304
    float* bbE = (float*)(ws + 76032);                   //   2304
    unsigned* pairmin = (unsigned*)(ws + 78336);         //   4416
    float* acc = (float*)(ws + 82752);                   //    128
    float4* TDg = (float4*)(ws + 82880);                 // 602112 -> 684992
    float4* TSg = (float4*)(ws + 684992);                // 150528 -> 835520
    float* pa = (float*)(ws + 835520);                   // 3145728 -> 3981248
    float* pb = (float*)(ws + 3981248);                  // 3145728 -> 7126976
    unsigned long long* best_a = (unsigned long long*)(ws + 7126976);  // 196608 -> 7323584
    unsigned long long* best_b = (unsigned long long*)(ws + 7323584);  // 131072 -> 7454656

    k_coons_tri<<<dim3(NB * NPATCH), dim3(128), 0, stream>>>(patches, grid, bbF, bbE,
                                                             TDg, TSg, pairmin, acc);
    k_mega<<<dim3(720, NB), dim3(256), 0, stream>>>(target, points, grid, TDg, TSg,
                                                    bbF, bbE, pa, pb, pairmin);
    k_argmin<<<dim3(10240), dim3(256), 0, stream>>>(target, points, pa, pb, best_a, best_b);
    k_final<<<dim3(40, NB), dim3(256), 0, stream>>>(points, normals, target, mtds, st,
                                                    tmpl, best_a, best_b, acc);
    k_finish<<<1, 256, 0, stream>>>(acc, pairmin, out);
}